// Round 2
// baseline (533.643 us; speedup 1.0000x reference)
//
#include <hip/hip_runtime.h>
#include <hip/hip_bf16.h>

#define TA_B 2
#define TA_H 16
#define TA_S 2048
#define TA_D 64
#define KTILE 64
#define QB 64
#define NKT (TA_S / KTILE)

typedef __attribute__((ext_vector_type(4))) float f32x4;
typedef __attribute__((ext_vector_type(8))) short bf16x8;
typedef __attribute__((ext_vector_type(8))) unsigned short u16x8;

union BF8 { u16x8 u; bf16x8 s; };

__device__ __forceinline__ unsigned short f2bf(float f) {
    union { float f; unsigned int i; } v; v.f = f;
    unsigned int x = v.i;
    unsigned int r = x + 0x7FFFu + ((x >> 16) & 1u);
    return (unsigned short)(r >> 16);
}

__global__ __launch_bounds__(256) void ta_fused(
    const float* __restrict__ Qg,
    const float* __restrict__ Kg,
    const float* __restrict__ Vg,
    const float* __restrict__ Tg,
    const int* __restrict__ Mg,
    float* __restrict__ Og,
    float* __restrict__ Pg)
{
    __shared__ unsigned short sKp[KTILE][72];   // bf16(K+T): [k][d], +8 pad
    __shared__ unsigned short sVt[TA_D][72];    // bf16 V^T:  [d][k], +8 pad
    __shared__ unsigned short sP[QB][72];       // bf16 P:    [q][k], wave-local rows

    const int tid  = threadIdx.x;
    const int wave = tid >> 6;
    const int lane = tid & 63;
    const int c    = lane & 15;
    const int g    = lane >> 4;

    const int q0 = blockIdx.x * QB;
    const int h  = blockIdx.y;
    const int b  = blockIdx.z;
    const long bh    = (long)b * TA_H + h;
    const long xBase = bh * (long)TA_S * TA_D;
    const long pBase = bh * (long)TA_S * TA_S;
    const long mBase = (long)b * (long)TA_S * TA_S;

    const int wq0 = wave * 16;

    // Q fragments: A-layout lane holds Q[m=c][k=g*8+i], k+32 for qf1
    bf16x8 qf0, qf1;
    {
        const float* qp = Qg + xBase + (long)(q0 + wq0 + c) * TA_D + g * 8;
        f32x4 a0 = *(const f32x4*)(qp);
        f32x4 a1 = *(const f32x4*)(qp + 4);
        f32x4 b0 = *(const f32x4*)(qp + 32);
        f32x4 b1 = *(const f32x4*)(qp + 36);
        BF8 u0, u1;
#pragma unroll
        for (int i = 0; i < 4; ++i) {
            u0.u[i]     = f2bf(a0[i]);
            u0.u[i + 4] = f2bf(a1[i]);
            u1.u[i]     = f2bf(b0[i]);
            u1.u[i + 4] = f2bf(b1[i]);
        }
        qf0 = u0.s; qf1 = u1.s;
    }

    float mrow[4], lrow[4];
#pragma unroll
    for (int r = 0; r < 4; ++r) { mrow[r] = -1e30f; lrow[r] = 0.0f; }

    const float scale = 0.125f; // 1/sqrt(64)

    // ---------------- Pass A: online row max + row sum ----------------
    for (int kt = 0; kt < NKT; ++kt) {
        __syncthreads();
#pragma unroll
        for (int s2 = 0; s2 < 2; ++s2) {
            int idx = s2 * 256 + tid;
            int row = idx >> 3;
            int cg  = (idx & 7) * 8;
            const long go = xBase + (long)(kt * KTILE + row) * TA_D + cg;
            f32x4 ka = *(const f32x4*)(Kg + go);
            f32x4 kb = *(const f32x4*)(Kg + go + 4);
            f32x4 ta = *(const f32x4*)(Tg + go);
            f32x4 tb = *(const f32x4*)(Tg + go + 4);
            u16x8 res;
#pragma unroll
            for (int i = 0; i < 4; ++i) {
                res[i]     = f2bf(ka[i] + ta[i]);
                res[i + 4] = f2bf(kb[i] + tb[i]);
            }
            *(u16x8*)&sKp[row][cg] = res;
        }
        __syncthreads();

        f32x4 acc[4];
#pragma unroll
        for (int ct = 0; ct < 4; ++ct)
#pragma unroll
            for (int j = 0; j < 4; ++j) acc[ct][j] = 0.0f;

#pragma unroll
        for (int kk = 0; kk < 2; ++kk) {
            bf16x8 qa = kk ? qf1 : qf0;
#pragma unroll
            for (int ct = 0; ct < 4; ++ct) {
                BF8 bf; bf.u = *(const u16x8*)&sKp[ct * 16 + c][kk * 32 + g * 8];
                acc[ct] = __builtin_amdgcn_mfma_f32_16x16x32_bf16(qa, bf.s, acc[ct], 0, 0, 0);
            }
        }

        float sv[4][4];
#pragma unroll
        for (int r = 0; r < 4; ++r) {
            const int mq = q0 + wq0 + g * 4 + r;
            const int* mp = Mg + mBase + (long)mq * TA_S + kt * KTILE;
#pragma unroll
            for (int ct = 0; ct < 4; ++ct) {
                const int mv = mp[ct * 16 + c];
                sv[ct][r] = mv ? acc[ct][r] * scale : -1e9f;
            }
        }

#pragma unroll
        for (int r = 0; r < 4; ++r) {
            float tmax = fmaxf(fmaxf(sv[0][r], sv[1][r]), fmaxf(sv[2][r], sv[3][r]));
#pragma unroll
            for (int off = 1; off < 16; off <<= 1)
                tmax = fmaxf(tmax, __shfl_xor(tmax, off));
            const float mnew = fmaxf(mrow[r], tmax);
            float tsum = __expf(sv[0][r] - mnew) + __expf(sv[1][r] - mnew)
                       + __expf(sv[2][r] - mnew) + __expf(sv[3][r] - mnew);
#pragma unroll
            for (int off = 1; off < 16; off <<= 1)
                tsum += __shfl_xor(tsum, off);
            lrow[r] = lrow[r] * __expf(mrow[r] - mnew) + tsum;
            mrow[r] = mnew;
        }
    }

    float invl[4];
#pragma unroll
    for (int r = 0; r < 4; ++r) invl[r] = 1.0f / lrow[r];

    f32x4 oacc[4];
#pragma unroll
    for (int dt = 0; dt < 4; ++dt)
#pragma unroll
        for (int j = 0; j < 4; ++j) oacc[dt][j] = 0.0f;

    // ---------------- Pass B: recompute S, write P (f32), O += P*V ----------------
    for (int kt = 0; kt < NKT; ++kt) {
        __syncthreads();
#pragma unroll
        for (int s2 = 0; s2 < 2; ++s2) {
            int idx = s2 * 256 + tid;
            int row = idx >> 3;
            int cg  = (idx & 7) * 8;
            const long go = xBase + (long)(kt * KTILE + row) * TA_D + cg;
            f32x4 ka = *(const f32x4*)(Kg + go);
            f32x4 kb = *(const f32x4*)(Kg + go + 4);
            f32x4 ta = *(const f32x4*)(Tg + go);
            f32x4 tb = *(const f32x4*)(Tg + go + 4);
            u16x8 res;
#pragma unroll
            for (int i = 0; i < 4; ++i) {
                res[i]     = f2bf(ka[i] + ta[i]);
                res[i + 4] = f2bf(kb[i] + tb[i]);
            }
            *(u16x8*)&sKp[row][cg] = res;

            f32x4 va = *(const f32x4*)(Vg + go);
            f32x4 vb = *(const f32x4*)(Vg + go + 4);
#pragma unroll
            for (int i = 0; i < 4; ++i) {
                sVt[cg + i][row]     = f2bf(va[i]);   // V^T: [d][k]
                sVt[cg + i + 4][row] = f2bf(vb[i]);
            }
        }
        __syncthreads();

        f32x4 acc[4];
#pragma unroll
        for (int ct = 0; ct < 4; ++ct)
#pragma unroll
            for (int j = 0; j < 4; ++j) acc[ct][j] = 0.0f;

#pragma unroll
        for (int kk = 0; kk < 2; ++kk) {
            bf16x8 qa = kk ? qf1 : qf0;
#pragma unroll
            for (int ct = 0; ct < 4; ++ct) {
                BF8 bf; bf.u = *(const u16x8*)&sKp[ct * 16 + c][kk * 32 + g * 8];
                acc[ct] = __builtin_amdgcn_mfma_f32_16x16x32_bf16(qa, bf.s, acc[ct], 0, 0, 0);
            }
        }

        // P = exp(s - m) / l : f32 -> global, bf16 -> LDS for PV fragment
#pragma unroll
        for (int r = 0; r < 4; ++r) {
            const int mq = q0 + wq0 + g * 4 + r;
            const int* mp = Mg + mBase + (long)mq * TA_S + kt * KTILE;
            float* pp = Pg + pBase + (long)mq * TA_S + kt * KTILE;
#pragma unroll
            for (int ct = 0; ct < 4; ++ct) {
                const int mv = mp[ct * 16 + c];
                float s = mv ? acc[ct][r] * scale : -1e9f;
                float p = __expf(s - mrow[r]) * invl[r];
                pp[ct * 16 + c] = p;
                sP[wq0 + g * 4 + r][ct * 16 + c] = f2bf(p);
            }
        }

        // PV: A = P (own wave's LDS rows), B = V^T tile
        BF8 pa0, pa1;
        pa0.u = *(const u16x8*)&sP[wq0 + c][g * 8];
        pa1.u = *(const u16x8*)&sP[wq0 + c][32 + g * 8];
#pragma unroll
        for (int dt = 0; dt < 4; ++dt) {
            BF8 bv0, bv1;
            bv0.u = *(const u16x8*)&sVt[dt * 16 + c][g * 8];
            oacc[dt] = __builtin_amdgcn_mfma_f32_16x16x32_bf16(pa0.s, bv0.s, oacc[dt], 0, 0, 0);
            bv1.u = *(const u16x8*)&sVt[dt * 16 + c][32 + g * 8];
            oacc[dt] = __builtin_amdgcn_mfma_f32_16x16x32_bf16(pa1.s, bv1.s, oacc[dt], 0, 0, 0);
        }
    }

    // store O (f32)
#pragma unroll
    for (int dt = 0; dt < 4; ++dt) {
#pragma unroll
        for (int r = 0; r < 4; ++r) {
            Og[xBase + (long)(q0 + wq0 + g * 4 + r) * TA_D + dt * 16 + c] = oacc[dt][r];
        }
    }
}

extern "C" void kernel_launch(void* const* d_in, const int* in_sizes, int n_in,
                              void* d_out, int out_size, void* d_ws, size_t ws_size,
                              hipStream_t stream) {
    const float* Q = (const float*)d_in[0];
    const float* K = (const float*)d_in[1];
    const float* V = (const float*)d_in[2];
    const float* T = (const float*)d_in[3];
    const int*   M = (const int*)d_in[4];

    float* O = (float*)d_out;
    float* P = O + (long)TA_B * TA_H * TA_S * TA_D;

    dim3 grid(TA_S / QB, TA_H, TA_B);
    dim3 block(256);
    hipLaunchKernelGGL(ta_fused, grid, block, 0, stream, Q, K, V, T, M, O, P);
}